// Round 13
// baseline (85.963 us; speedup 1.0000x reference)
//
#include <hip/hip_runtime.h>
#include <stdint.h>

// GCNConv forward on MI355X — aggregate-then-transform, bf16 MFMA, 5 launches.
//
//   out[t] = relu( ( dinv[t] * ( dinv[t]*x[t] + sum_{(s,t)} dinv[s]*x[s] ) ) @ W + b )
//
// Pipeline (fast path):
//   1. k_setup    : deg = 0 (200 KB zero, first link of the serial chain)
//   2. k_count    : deg histogram + slot[i] (2 edges/thread, hist only)
//   3. k_scanaux  : chunk-local scan -> rowptr + dinv (49 blocks, critical path)
//                   ∥ xb = bf16(x) cast (3125 blocks)  ∥ Warr pack (8 blocks)
//                   — cast/pack hide under the otherwise-idle scan launch
//   4. k_fill     : inline coff scan (wave0) -> elist (no atomics)
//   5. k_gather_gemm : per-node gather (16 lanes/node, unroll-4 + index
//                   prefetch, per-edge dinv fma in REGISTERS) -> swizzled LDS
//                   tile -> MFMA vs VGPR W frags, nt-store out
//
// Lessons pinned:
//  - decoupled-lookback scan = 48 us (1 us/hop agent-atomic chain across 8
//    non-coherent XCD L2s) — keep two-pass scan, never chain blocks.
//  - rocclr fillBuffer in top-5 is HARNESS POISON of d_ws, not ours.
//  - nt-hints ONLY on write-once streams (out). R8's nontemporal_load on the
//    gather path: FETCH 68.6 MB >> 15 MB compulsory, +18 us.
//  - LDS fp32 atomicAdd as accumulation fabric (R11): 76.8M ds_atomics ->
//    481 us (100x). Accumulate in REGISTERS, always.
//  - Gather pipelining beyond 1-stage prefetch: no gain (R10). Gather runs at
//    the cross-XCD L3 random-row service rate (~153.6 MB @ ~4 TB/s): xb
//    (12.8 MB) exceeds a single XCD L2 (4 MB), random src => no locality.

#define FDIM 128
#define HDIM 128
#define SCAN_CHUNK 1024

using s8v   = __attribute__((ext_vector_type(8))) short;  // 8 bf16 = 4 VGPR
using f32x4 = __attribute__((ext_vector_type(4))) float;  // MFMA C/D

__device__ __forceinline__ unsigned bf16rn(float f) {
    unsigned u = __float_as_uint(f);
    return (u + 0x7fffu + ((u >> 16) & 1u)) >> 16;  // RNE
}
// lo += ds * bf16lo(w); hi += ds * bf16hi(w)
__device__ __forceinline__ void upfma(unsigned w, float ds, float& lo, float& hi) {
    lo = fmaf(ds, __uint_as_float(w << 16), lo);
    hi = fmaf(ds, __uint_as_float(w & 0xffff0000u), hi);
}

// ---------------- 1. setup: zero deg ----------------
__global__ __launch_bounds__(256) void k_setup(int* __restrict__ deg, int n) {
    const int i = blockIdx.x * 256 + threadIdx.x;
    if (i < n) deg[i] = 0;
}

// ---------------- 2. histogram + slot (2 edges/thread) ----------------
__global__ __launch_bounds__(256) void k_count(const int* __restrict__ dst,
                                               int* __restrict__ deg,
                                               int* __restrict__ slot, int e) {
    const int i = blockIdx.x * 512 + threadIdx.x;
    if (i < e) slot[i] = atomicAdd(&deg[dst[i]], 1);
    const int j = i + 256;
    if (j < e) slot[j] = atomicAdd(&deg[dst[j]], 1);
}

// ---------------- 3. scan (critical) ∥ bf16 cast ∥ Warr pack ----------------
// blocks [0, nblk)                : chunk-local scan of deg -> rowptr, + dinv
// blocks [nblk, nblk+castBlocks)  : xb = bf16(x)
// blocks [nblk+castBlocks, +8)    : Warr chunk-major bf16 pack
__global__ __launch_bounds__(256) void k_scanaux(const int* __restrict__ deg,
                                                 int* __restrict__ rowptr,
                                                 int* __restrict__ partials,
                                                 float* __restrict__ dinv,
                                                 const float* __restrict__ x,
                                                 uint4* __restrict__ xb,
                                                 const float* __restrict__ W,
                                                 uint4* __restrict__ Warr,
                                                 int n, int nblk, int castBlocks) {
    const int b = blockIdx.x;
    const int tid = threadIdx.x;
    if (b < nblk) {  // ---- scan part (critical path) ----
        __shared__ int sdata[256];
        const int base = b * SCAN_CHUNK + tid * 4;
        int v[4];
        int s = 0;
#pragma unroll
        for (int j = 0; j < 4; ++j) {
            int idx = base + j;
            v[j] = (idx < n) ? deg[idx] : 0;
            if (idx < n) dinv[idx] = rsqrtf((float)v[j] + 1.0f);  // +1 self-loop
            s += v[j];
        }
        sdata[tid] = s;
        __syncthreads();
        for (int off = 1; off < 256; off <<= 1) {
            int t = (tid >= off) ? sdata[tid - off] : 0;
            __syncthreads();
            sdata[tid] += t;
            __syncthreads();
        }
        int run = sdata[tid] - s;
#pragma unroll
        for (int j = 0; j < 4; ++j) {
            int idx = base + j;
            if (idx < n) rowptr[idx] = run;
            run += v[j];
        }
        if (tid == 255) {
            partials[b] = sdata[255];
            if (b == nblk - 1) rowptr[n] = sdata[255];  // chunk-local
        }
    } else if (b < nblk + castBlocks) {  // ---- bf16 cast ----
        const long long idx = (long long)(b - nblk) * 256 + tid;
        if (idx >= (long long)n * (FDIM / 8)) return;
        const float4* xp = (const float4*)x + idx * 2;
        const float4 a = xp[0], c = xp[1];
        uint4 o;
        o.x = bf16rn(a.x) | (bf16rn(a.y) << 16);
        o.y = bf16rn(a.z) | (bf16rn(a.w) << 16);
        o.z = bf16rn(c.x) | (bf16rn(c.y) << 16);
        o.w = bf16rn(c.z) | (bf16rn(c.w) << 16);
        xb[idx] = o;
    } else {  // ---- Warr pack (8 blocks) ----
        const int t = (b - nblk - castBlocks) * 256 + tid;
        if (t >= (FDIM / 8) * HDIM) return;
        const int chunk = t >> 7, nn = t & 127;
        float v[8];
#pragma unroll
        for (int j = 0; j < 8; ++j) v[j] = W[(chunk * 8 + j) * HDIM + nn];
        uint4 o;
        o.x = bf16rn(v[0]) | (bf16rn(v[1]) << 16);
        o.y = bf16rn(v[2]) | (bf16rn(v[3]) << 16);
        o.z = bf16rn(v[4]) | (bf16rn(v[5]) << 16);
        o.w = bf16rn(v[6]) | (bf16rn(v[7]) << 16);
        Warr[t] = o;
    }
}

// ---------------- (fallback only) scan of chunk totals ----------------
__global__ __launch_bounds__(64) void k_scan2(int* __restrict__ partials, int nb) {
    int l = threadIdx.x;
    int v = (l < nb) ? partials[l] : 0;
    int inc = v;
    for (int off = 1; off < 64; off <<= 1) {
        int t = __shfl_up(inc, off);
        if (l >= off) inc += t;
    }
    if (l < nb) partials[l] = inc - v;  // becomes coff[]
}

// ---------------- 4. fill (inline coff, no atomics) ----------------
__global__ __launch_bounds__(256) void k_fill(const int* __restrict__ src,
                                              const int* __restrict__ dst,
                                              const int* __restrict__ slot,
                                              const int* __restrict__ rowptr,
                                              const int* __restrict__ partials,
                                              int* __restrict__ elist, int e, int nb) {
    __shared__ int coffs[64];
    const int tid = threadIdx.x;
    if (tid < 64) {  // wave 0: exclusive scan of chunk totals (nb <= 64)
        int v = (tid < nb) ? partials[tid] : 0;
        int inc = v;
        for (int off = 1; off < 64; off <<= 1) {
            int t = __shfl_up(inc, off);
            if (tid >= off) inc += t;
        }
        coffs[tid] = inc - v;
    }
    __syncthreads();
    const int i = blockIdx.x * 256 + tid;
    if (i < e) {
        const int d = dst[i];
        elist[rowptr[d] + coffs[d >> 10] + slot[i]] = src[i];
    }
}

// ---------------- 5. fused gather + MFMA GEMM ----------------
// Block = 256 thr (4 waves) = 16 nodes. Gather: 16 lanes/node, unroll-4 with
// one-stage index prefetch; per-edge dinv fma in registers. W frags preloaded
// early (overlap with gather latency). nt-store of out only.
__global__ __launch_bounds__(256) void k_gather_gemm(
    const uint4* __restrict__ xb, const float* __restrict__ dinv,
    const int* __restrict__ rowptr, const int* __restrict__ partials,
    const int* __restrict__ elist, const uint4* __restrict__ Warr,
    const float* __restrict__ bias, float* __restrict__ out, int n, int nb) {
    __shared__ uint4 zlds[16][16];  // 4 KB
    __shared__ int coffs[64];
    const int tid = threadIdx.x;
    const int r = tid >> 4, q = tid & 15;
    const int node = blockIdx.x * 16 + r;
    const int wave = tid >> 6, lane = tid & 63;
    const int l16 = lane & 15, lg = lane >> 4;

    if (tid < 64) {  // wave 0: exclusive scan of chunk totals (nb <= 64)
        int v = (tid < nb) ? partials[tid] : 0;
        int inc = v;
        for (int off = 1; off < 64; off <<= 1) {
            int t = __shfl_up(inc, off);
            if (tid >= off) inc += t;
        }
        coffs[tid] = inc - v;
    }
    __syncthreads();

    // Early: row bounds + dinv (issue before W preload to hide latency).
    int beg = 0, end = 0;
    float di = 0.0f;
    if (node < n) {
        beg = rowptr[node] + coffs[node >> 10];
        end = rowptr[node + 1] + coffs[(node + 1) >> 10];  // may cross chunk
        di = dinv[node];
    }

    // Preload W fragments (L2-hot) + bias; overlaps with gather chain.
    s8v wf[2][4];
#pragma unroll
    for (int ntl = 0; ntl < 2; ++ntl)
#pragma unroll
        for (int ks = 0; ks < 4; ++ks)
            wf[ntl][ks] = *(const s8v*)&Warr[(ks * 4 + lg) * 128 +
                                             (wave * 2 + ntl) * 16 + l16];
    const float bv0 = bias[(wave * 2 + 0) * 16 + l16];
    const float bv1 = bias[(wave * 2 + 1) * 16 + l16];

    if (node < n) {
        const uint4* xq = xb + q;  // row stride = 16 uint4
        float a0 = 0.f, a1 = 0.f, a2 = 0.f, a3 = 0.f,
              a4 = 0.f, a5 = 0.f, a6 = 0.f, a7 = 0.f;
        {   // self term: di * x[t]
            const uint4 v = xq[(size_t)node * 16];
            upfma(v.x, di, a0, a1); upfma(v.y, di, a2, a3);
            upfma(v.z, di, a4, a5); upfma(v.w, di, a6, a7);
        }
        if (beg < end) {
            const int last = end - 1;
            int sidx[4];
#pragma unroll
            for (int k = 0; k < 4; ++k) {
                const int jj = beg + k;
                sidx[k] = elist[jj < end ? jj : last];
            }
            for (int j = beg; j < end; j += 4) {
                int snext[4];
#pragma unroll
                for (int k = 0; k < 4; ++k) {   // prefetch next iteration's indices
                    const int jj = j + 4 + k;
                    snext[k] = elist[jj < end ? jj : last];
                }
                float dw[4];
                uint4 u[4];
#pragma unroll
                for (int k = 0; k < 4; ++k) {   // dinv + row loads issue together
                    dw[k] = (j + k < end) ? dinv[sidx[k]] : 0.0f;
                    u[k] = xq[(size_t)sidx[k] * 16];
                }
#pragma unroll
                for (int k = 0; k < 4; ++k) {
                    upfma(u[k].x, dw[k], a0, a1); upfma(u[k].y, dw[k], a2, a3);
                    upfma(u[k].z, dw[k], a4, a5); upfma(u[k].w, dw[k], a6, a7);
                }
#pragma unroll
                for (int k = 0; k < 4; ++k) sidx[k] = snext[k];
            }
        }
        uint4 o;
        o.x = bf16rn(a0 * di) | (bf16rn(a1 * di) << 16);
        o.y = bf16rn(a2 * di) | (bf16rn(a3 * di) << 16);
        o.z = bf16rn(a4 * di) | (bf16rn(a5 * di) << 16);
        o.w = bf16rn(a6 * di) | (bf16rn(a7 * di) << 16);
        zlds[r][q ^ r] = o;
    }
    __syncthreads();

    s8v afr[4];
#pragma unroll
    for (int ks = 0; ks < 4; ++ks)
        afr[ks] = *(const s8v*)&zlds[l16][(ks * 4 + lg) ^ l16];

#pragma unroll
    for (int ntl = 0; ntl < 2; ++ntl) {
        f32x4 acc = (f32x4){0.f, 0.f, 0.f, 0.f};
#pragma unroll
        for (int ks = 0; ks < 4; ++ks)
            acc = __builtin_amdgcn_mfma_f32_16x16x32_bf16(afr[ks], wf[ntl][ks], acc, 0, 0, 0);
        const int col = (wave * 2 + ntl) * 16 + l16;
        const float bv = ntl ? bv1 : bv0;
#pragma unroll
        for (int rr = 0; rr < 4; ++rr) {
            const int row = blockIdx.x * 16 + lg * 4 + rr;
            if (row < n)
                __builtin_nontemporal_store(fmaxf(acc[rr] + bv, 0.0f),
                                            &out[(size_t)row * HDIM + col]);
        }
    }
}

// ---------------- fallback path: fp32 (uses k_scan2'd coff) ----------------
__global__ __launch_bounds__(256) void k_fill_fb(const int* __restrict__ src,
                                                 const int* __restrict__ dst,
                                                 const int* __restrict__ slot,
                                                 const int* __restrict__ rowptr,
                                                 const int* __restrict__ coff,
                                                 int* __restrict__ elist, int e) {
    int i = blockIdx.x * 256 + threadIdx.x;
    if (i < e) {
        const int d = dst[i];
        elist[rowptr[d] + coff[d >> 10] + slot[i]] = src[i];
    }
}

__global__ __launch_bounds__(256) void k_gather_f32(const float* __restrict__ x,
                                                    const float* __restrict__ dinv,
                                                    const int* __restrict__ rowptr,
                                                    const int* __restrict__ coff,
                                                    const int* __restrict__ elist,
                                                    float* __restrict__ z, int n) {
    const int lane = threadIdx.x & 31;
    const int node = blockIdx.x * 8 + (threadIdx.x >> 5);
    if (node >= n) return;
    const float di = dinv[node];
    float4 v = ((const float4*)(x + (size_t)node * FDIM))[lane];
    float4 sum;
    sum.x = di * v.x; sum.y = di * v.y; sum.z = di * v.z; sum.w = di * v.w;
    const int beg = rowptr[node] + coff[node >> 10];
    const int end = rowptr[node + 1] + coff[(node + 1) >> 10];
    for (int j = beg; j < end; ++j) {
        const int s = elist[j];
        const float ds = dinv[s];
        const float4 u = ((const float4*)(x + (size_t)s * FDIM))[lane];
        sum.x = fmaf(ds, u.x, sum.x);
        sum.y = fmaf(ds, u.y, sum.y);
        sum.z = fmaf(ds, u.z, sum.z);
        sum.w = fmaf(ds, u.w, sum.w);
    }
    float4 o;
    o.x = di * sum.x; o.y = di * sum.y; o.z = di * sum.z; o.w = di * sum.w;
    ((float4*)(z + (size_t)node * FDIM))[lane] = o;
}

__global__ __launch_bounds__(512) void k_gemm_relu(const float* __restrict__ W,
                                                   const float* __restrict__ bias,
                                                   float* __restrict__ zo, int n) {
    __shared__ float Wl[FDIM * HDIM];
    __shared__ float xs[4][FDIM];
    const int t = threadIdx.x;
    const int h = t & (HDIM - 1);
    const int g = t >> 7;
    {
        const float4* W4 = (const float4*)W;
        float4* Wl4 = (float4*)Wl;
        for (int i = t; i < FDIM * HDIM / 4; i += 512) Wl4[i] = W4[i];
    }
    __syncthreads();
    const float bv = bias[h];
    const int nq = (n + 3) >> 2;
    for (int q = blockIdx.x; q < nq; q += gridDim.x) {
        const int row = q * 4 + g;
        if (row < n) xs[g][h] = zo[(size_t)row * HDIM + h];
        __syncthreads();
        if (row < n) {
            float acc = bv;
#pragma unroll
            for (int k = 0; k < FDIM; ++k)
                acc = fmaf(xs[g][k], Wl[k * HDIM + h], acc);
            zo[(size_t)row * HDIM + h] = fmaxf(acc, 0.0f);
        }
        __syncthreads();
    }
}

extern "C" void kernel_launch(void* const* d_in, const int* in_sizes, int n_in,
                              void* d_out, int out_size, void* d_ws, size_t ws_size,
                              hipStream_t stream) {
    const float* x = (const float*)d_in[0];
    const float* W = (const float*)d_in[1];
    const float* b = (const float*)d_in[2];
    const int* ei = (const int*)d_in[3];
    float* out = (float*)d_out;

    const int H = in_sizes[2];      // 128
    const int F = in_sizes[1] / H;  // 128
    const int N = in_sizes[0] / F;  // 50000
    const int E = in_sizes[3] / 2;  // 600000
    const int* srcp = ei;
    const int* dstp = ei + E;

    auto align256 = [](size_t v) { return (v + 255) & ~(size_t)255; };
    char* ws = (char*)d_ws;
    size_t off = 0;
    int* deg = (int*)(ws + off);      off += align256((size_t)N * 4);
    float* dinv = (float*)(ws + off); off += align256((size_t)N * 4);
    int* rowptr = (int*)(ws + off);   off += align256((size_t)(N + 1) * 4);
    int* slot = (int*)(ws + off);     off += align256((size_t)E * 4);
    int* partials = (int*)(ws + off); off += 256;  // <= 64 chunk totals
    int* elist = (int*)(ws + off);    off += align256((size_t)E * 4);
    uint4* xb = (uint4*)(ws + off);   off += align256((size_t)N * FDIM * 2);
    uint4* Warr = (uint4*)(ws + off); off += align256((size_t)(FDIM / 8) * HDIM * 16);
    const bool fast = (ws_size >= off) && (N <= 64 * SCAN_CHUNK);

    const int nblk_scan = (N + SCAN_CHUNK - 1) / SCAN_CHUNK;  // 49
    const int fillBlocks = (E + 255) / 256;
    const int countBlocks = (E + 511) / 512;

    k_setup<<<(N + 255) / 256, 256, 0, stream>>>(deg, N);
    k_count<<<countBlocks, 256, 0, stream>>>(dstp, deg, slot, E);
    if (fast) {
        const long long nchunks = (long long)N * (FDIM / 8);
        const int castBlocks = (int)((nchunks + 255) / 256);      // 3125
        const int warrBlocks = ((FDIM / 8) * HDIM + 255) / 256;   // 8
        k_scanaux<<<nblk_scan + castBlocks + warrBlocks, 256, 0, stream>>>(
            deg, rowptr, partials, dinv, x, xb, W, Warr, N, nblk_scan, castBlocks);
        k_fill<<<fillBlocks, 256, 0, stream>>>(srcp, dstp, slot, rowptr, partials,
                                               elist, E, nblk_scan);
        k_gather_gemm<<<(N + 15) / 16, 256, 0, stream>>>(xb, dinv, rowptr, partials,
                                                         elist, Warr, b, out, N,
                                                         nblk_scan);
    } else {
        k_scanaux<<<nblk_scan, 256, 0, stream>>>(deg, rowptr, partials, dinv,
                                                 x, nullptr, W, nullptr,
                                                 N, nblk_scan, 0);
        k_scan2<<<1, 64, 0, stream>>>(partials, nblk_scan);
        k_fill_fb<<<fillBlocks, 256, 0, stream>>>(srcp, dstp, slot, rowptr, partials,
                                                  elist, E);
        k_gather_f32<<<(N + 7) / 8, 256, 0, stream>>>(x, dinv, rowptr, partials,
                                                      elist, out, N);
        k_gemm_relu<<<512, 512, 0, stream>>>(W, b, out, N);
    }
}